// Round 2
// baseline (668.310 us; speedup 1.0000x reference)
//
#include <hip/hip_runtime.h>
#include <hip/hip_cooperative_groups.h>

namespace cg = cooperative_groups;

namespace {

constexpr int B = 2;
constexpr int N = 200000;
constexpr int C = 16;
constexpr int D = 256;
constexpr int H = 256;
constexpr int W = 32;
constexpr int V = D * H * W;    // 2^21 voxels per batch
constexpr int BV = B * V;       // 4,194,304
constexpr unsigned NIL = 0xFFFFFFFFu;

// Replicate reference op order exactly: (p - lo) / (hi - lo) * dim, trunc, clip.
// (This exact formulation gave absmax 0 across all rounds — do not change.)
__device__ __forceinline__ int voxel_of(float x, float y, float z) {
    float fx = (x - (-48.0f)) / 96.0f * 256.0f;
    float fy = (y - (-48.0f)) / 96.0f * 256.0f;
    float fz = (z - (-4.0f)) / 5.5f * 32.0f;
    int vx = (int)fx;
    int vy = (int)fy;
    int vz = (int)fz;
    vx = vx < 0 ? 0 : (vx > D - 1 ? D - 1 : vx);
    vy = vy < 0 ? 0 : (vy > H - 1 ? H - 1 : vy);
    vz = vz < 0 ? 0 : (vz > W - 1 ? W - 1 : vz);
    return (vx * H + vy) * W + vz;
}

// Shared by fused + fallback: the per-voxel gather/mean/store body.
__device__ __forceinline__ void gather_one_voxel(
    int t, const unsigned* __restrict__ head, const unsigned* __restrict__ nxt,
    const float4* __restrict__ fts4, float* __restrict__ out) {
    int b = t >> 21;              // V = 2^21
    int v = t & (V - 1);

    unsigned h = head[t];         // coalesced

    float s[16];
#pragma unroll
    for (int c = 0; c < 16; ++c) s[c] = 0.f;
    float cnt = 0.f;
    unsigned nx = NIL;

    if (h != NIL) {               // ~9.1% of lanes
        const float4* fp = fts4 + (size_t)h * 4;
        float4 f0 = fp[0];
        float4 f1 = fp[1];
        float4 f2 = fp[2];
        float4 f3 = fp[3];        // one 64B line, fully used
        nx = nxt[h];
        s[0]  = f0.x; s[1]  = f0.y; s[2]  = f0.z; s[3]  = f0.w;
        s[4]  = f1.x; s[5]  = f1.y; s[6]  = f1.z; s[7]  = f1.w;
        s[8]  = f2.x; s[9]  = f2.y; s[10] = f2.z; s[11] = f2.w;
        s[12] = f3.x; s[13] = f3.y; s[14] = f3.z; s[15] = f3.w;
        cnt = 1.f;
    }

    // Rare tail: voxels with >= 2 points.
    while (nx != NIL) {
        const float4* fp = fts4 + (size_t)nx * 4;
        float4 f0 = fp[0];
        float4 f1 = fp[1];
        float4 f2 = fp[2];
        float4 f3 = fp[3];
        unsigned nn = nxt[nx];
        s[0]  += f0.x; s[1]  += f0.y; s[2]  += f0.z; s[3]  += f0.w;
        s[4]  += f1.x; s[5]  += f1.y; s[6]  += f1.z; s[7]  += f1.w;
        s[8]  += f2.x; s[9]  += f2.y; s[10] += f2.z; s[11] += f2.w;
        s[12] += f3.x; s[13] += f3.y; s[14] += f3.z; s[15] += f3.w;
        cnt += 1.f;
        nx = nn;
    }

    if (cnt > 1.f) {              // cnt==1: s/1 is exact, skip IEEE div
        float c = cnt;
#pragma unroll
        for (int k = 0; k < 16; ++k) s[k] /= c;
    }

    float* obase = out + (size_t)b * C * V + v;
#pragma unroll
    for (int c = 0; c < 16; ++c)
        obase[(size_t)c * V] = s[c];   // 256B contiguous per wave per c
}

// ---- R2: single cooperative kernel. Rationale: R1's structural finalize
// rewrite was perfectly neutral (330 vs 329 µs) while roofline arithmetic
// puts the three kernels at ~90-110 µs total -> suspect the residual lives
// at dispatch boundaries (launch + inter-kernel L2 writeback of scattered
// atomic lines). Fusing with grid.sync() removes two boundaries and makes
// total GPU time visible as one dispatch in the profile.
__global__ __launch_bounds__(256, 4) void fused_all(
    const float* __restrict__ pts, const float4* __restrict__ fts4,
    unsigned* __restrict__ head, unsigned* __restrict__ nxt,
    float* __restrict__ out) {
    cg::grid_group grid = cg::this_grid();
    const int tid = blockIdx.x * blockDim.x + threadIdx.x;
    const int nthr = gridDim.x * blockDim.x;   // 262,144 at 1024x256

    // Phase 1: head = NIL. BV/4 uint4 = 4 iters.
    uint4* head4 = (uint4*)head;
    for (int i = tid; i < BV / 4; i += nthr)
        head4[i] = make_uint4(NIL, NIL, NIL, NIL);

    __threadfence();
    grid.sync();

    // Phase 2: push each point onto its voxel list. 2 iters.
    for (int idx = tid; idx < B * N; idx += nthr) {
        const float* p = pts + (size_t)idx * 3;
        int v = voxel_of(p[0], p[1], p[2]);
        int b = idx >= N ? 1 : 0;            // B == 2
        unsigned old = atomicExch(head + (size_t)b * V + v, (unsigned)idx);
        nxt[idx] = old;
    }

    __threadfence();
    grid.sync();

    // Phase 3: gather + mean + dense store. 16 iters.
    for (int t = tid; t < BV; t += nthr)
        gather_one_voxel(t, head, nxt, fts4, out);
}

// ---- Fallback A: the proven 3-kernel path (if cooperative launch rejected).
__global__ __launch_bounds__(256) void init_head(uint4* __restrict__ head4, int n4) {
    int i = blockIdx.x * blockDim.x + threadIdx.x;
    if (i < n4) head4[i] = make_uint4(NIL, NIL, NIL, NIL);
}

__global__ __launch_bounds__(256) void build_list(
    const float* __restrict__ pts, unsigned* __restrict__ head,
    unsigned* __restrict__ nxt) {
    int idx = blockIdx.x * blockDim.x + threadIdx.x;
    if (idx >= B * N) return;
    const float* p = pts + (size_t)idx * 3;
    int v = voxel_of(p[0], p[1], p[2]);
    int b = idx >= N ? 1 : 0;
    unsigned old = atomicExch(head + (size_t)b * V + v, (unsigned)idx);
    nxt[idx] = old;
}

__global__ __launch_bounds__(256) void finalize(
    const unsigned* __restrict__ head, const unsigned* __restrict__ nxt,
    const float4* __restrict__ fts4, float* __restrict__ out) {
    int t = blockIdx.x * blockDim.x + threadIdx.x;
    if (t >= BV) return;
    gather_one_voxel(t, head, nxt, fts4, out);
}

// ---- Fallback B (tiny-workspace safety net): direct strided atomics into out.
__global__ __launch_bounds__(256) void zero_f4(float4* __restrict__ p, int n4) {
    int i = blockIdx.x * blockDim.x + threadIdx.x;
    if (i < n4) p[i] = make_float4(0.f, 0.f, 0.f, 0.f);
}

__global__ __launch_bounds__(256) void count_only(
    const float* __restrict__ pts, float* __restrict__ counts) {
    int idx = blockIdx.x * blockDim.x + threadIdx.x;
    if (idx >= B * N) return;
    int b = idx >= N ? 1 : 0;
    const float* p = pts + (size_t)idx * 3;
    int v = voxel_of(p[0], p[1], p[2]);
    atomicAdd(counts + (size_t)b * V + v, 1.0f);
}

__global__ __launch_bounds__(256) void scatter_direct(
    const float* __restrict__ pts, const float* __restrict__ fts,
    const float* __restrict__ counts, float* __restrict__ out) {
    int idx = blockIdx.x * blockDim.x + threadIdx.x;
    if (idx >= B * N) return;
    int b = idx >= N ? 1 : 0;
    const float* p = pts + (size_t)idx * 3;
    int v = voxel_of(p[0], p[1], p[2]);
    float cnt = counts[(size_t)b * V + v];
    const float* f = fts + (size_t)idx * C;
    float* o = out + (size_t)b * C * V + v;
#pragma unroll
    for (int c = 0; c < 16; ++c) atomicAdd(o + (size_t)c * V, f[c] / cnt);
}

}  // namespace

extern "C" void kernel_launch(void* const* d_in, const int* in_sizes, int n_in,
                              void* d_out, int out_size, void* d_ws, size_t ws_size,
                              hipStream_t stream) {
    const float* pts = (const float*)d_in[0];   // [B, N, 3]
    const float* fts = (const float*)d_in[1];   // [B, N, C]
    float* out = (float*)d_out;                 // [B, C, D, H, W]

    const int n_pts = B * N;                    // 400,000
    const int pt_blocks = (n_pts + 255) / 256;

    const size_t head_bytes = (size_t)BV * sizeof(unsigned);      // 16.8 MB
    const size_t nxt_bytes = (size_t)n_pts * sizeof(unsigned);    // 1.6 MB

    if (ws_size >= head_bytes + nxt_bytes) {
        unsigned* head = (unsigned*)d_ws;
        unsigned* nxt = head + (size_t)BV;

        const float4* fts4 = (const float4*)fts;
        void* args[] = {(void*)&pts, (void*)&fts4, (void*)&head,
                        (void*)&nxt, (void*)&out};
        // 1024 blocks x 256 thr = 4 blocks/CU, guaranteed co-resident by
        // __launch_bounds__(256, 4) (VGPR capped at 128).
        hipError_t e = hipLaunchCooperativeKernel(
            (const void*)fused_all, dim3(1024), dim3(256), args, 0, stream);

        if (e != hipSuccess) {
            // Cooperative launch rejected (e.g. under this capture mode):
            // proven 3-kernel path.
            int head_n4 = BV / 4;  // 1,048,576
            init_head<<<(head_n4 + 255) / 256, 256, 0, stream>>>(
                (uint4*)head, head_n4);
            build_list<<<pt_blocks, 256, 0, stream>>>(pts, head, nxt);
            finalize<<<(BV + 255) / 256, 256, 0, stream>>>(
                head, nxt, (const float4*)fts, out);
        }
    } else {
        // Safety net: direct atomic accumulation into out.
        float* counts = (float*)d_ws;
        int counts_f4 = BV / 4;
        zero_f4<<<(counts_f4 + 255) / 256, 256, 0, stream>>>((float4*)counts, counts_f4);
        int out_f4 = out_size / 4;
        zero_f4<<<(out_f4 + 255) / 256, 256, 0, stream>>>((float4*)out, out_f4);
        count_only<<<pt_blocks, 256, 0, stream>>>(pts, counts);
        scatter_direct<<<pt_blocks, 256, 0, stream>>>(pts, fts, counts, out);
    }
}

// Round 3
// 334.787 us; speedup vs baseline: 1.9962x; 1.9962x over previous
//
#include <hip/hip_runtime.h>

namespace {

constexpr int B = 2;
constexpr int N = 200000;
constexpr int C = 16;
constexpr int D = 256;
constexpr int H = 256;
constexpr int W = 32;
constexpr int V = D * H * W;    // 2^21 voxels per batch
constexpr int BV = B * V;       // 4,194,304
constexpr unsigned NIL = 0xFFFFFFFFu;
constexpr int VOX = 512;        // voxels per finalize block (32 KB LDS tile)

// Replicate reference op order exactly: (p - lo) / (hi - lo) * dim, trunc, clip.
// (This exact formulation gave absmax 0 across all rounds — do not change.)
__device__ __forceinline__ int voxel_of(float x, float y, float z) {
    float fx = (x - (-48.0f)) / 96.0f * 256.0f;
    float fy = (y - (-48.0f)) / 96.0f * 256.0f;
    float fz = (z - (-4.0f)) / 5.5f * 32.0f;
    int vx = (int)fx;
    int vy = (int)fy;
    int vz = (int)fz;
    vx = vx < 0 ? 0 : (vx > D - 1 ? D - 1 : vx);
    vy = vy < 0 ? 0 : (vy > H - 1 ? H - 1 : vy);
    vz = vz < 0 ? 0 : (vz > W - 1 ? W - 1 : vz);
    return (vx * H + vy) * W + vz;
}

// NOTE (R4 lesson): no __builtin_nontemporal_* anywhere. NT loads killed the
// L2 hits on head/nxt, NT stores amplified WRITE_SIZE.
// NOTE (R2 lesson): cooperative fusion regressed (438 µs in-kernel at 16
// waves/CU; +230 µs coop-launch overhead). Keep 3 plain kernels.

__global__ __launch_bounds__(256) void init_head(uint4* __restrict__ head4, int n4) {
    int i = blockIdx.x * blockDim.x + threadIdx.x;
    if (i < n4) head4[i] = make_uint4(NIL, NIL, NIL, NIL);
}

// One atomicExch per point: push point idx onto its voxel's intrusive list.
__global__ __launch_bounds__(256) void build_list(
    const float* __restrict__ pts, unsigned* __restrict__ head,
    unsigned* __restrict__ nxt) {
    int idx = blockIdx.x * blockDim.x + threadIdx.x;
    if (idx >= B * N) return;
    const float* p = pts + (size_t)idx * 3;
    int v = voxel_of(p[0], p[1], p[2]);
    int b = idx >= N ? 1 : 0;   // B == 2
    unsigned old = atomicExch(head + (size_t)b * V + v, (unsigned)idx);
    nxt[idx] = old;
}

// R3 finalize: gather 512 voxels into a channel-major LDS tile, then stream
// each channel out as a 2 KB contiguous burst (wave w owns channels 4w..4w+3).
// Rationale: R2 profile showed minimal traffic (286 MB write) at only 800
// GB/s with idle VALU — the [b][c][v] write pattern (16 streams in 256B-1KB
// chunks, 8 MB apart) thrashes DRAM rows. Burst length per stream visit goes
// 256B -> 2KB; streams per wave 16 -> 1-at-a-time.
__global__ __launch_bounds__(256) void finalize_tile(
    const unsigned* __restrict__ head, const unsigned* __restrict__ nxt,
    const float4* __restrict__ fts4, float* __restrict__ out) {
    __shared__ float tile[C][VOX];          // 32 KB -> 4-5 blocks/CU

    const int tid = threadIdx.x;
    const int base = blockIdx.x * VOX;      // flat (b,v); VOX | V so no straddle
    const int b = base >> 21;               // V = 2^21
    const int v0 = base & (V - 1);

    // ---- Phase A: gather. 2 voxels per thread; issue both head loads first.
    unsigned h[2];
    h[0] = head[base + tid];
    h[1] = head[base + 256 + tid];

#pragma unroll
    for (int k = 0; k < 2; ++k) {
        float s[16];
#pragma unroll
        for (int c = 0; c < 16; ++c) s[c] = 0.f;
        float cnt = 0.f;
        unsigned nx = NIL;

        if (h[k] != NIL) {                  // ~9.1% of lanes
            const float4* fp = fts4 + (size_t)h[k] * 4;
            float4 f0 = fp[0];
            float4 f1 = fp[1];
            float4 f2 = fp[2];
            float4 f3 = fp[3];              // one 64B line, fully used
            nx = nxt[h[k]];
            s[0]  = f0.x; s[1]  = f0.y; s[2]  = f0.z; s[3]  = f0.w;
            s[4]  = f1.x; s[5]  = f1.y; s[6]  = f1.z; s[7]  = f1.w;
            s[8]  = f2.x; s[9]  = f2.y; s[10] = f2.z; s[11] = f2.w;
            s[12] = f3.x; s[13] = f3.y; s[14] = f3.z; s[15] = f3.w;
            cnt = 1.f;
        }

        // Rare tail: voxels with >= 2 points.
        while (nx != NIL) {
            const float4* fp = fts4 + (size_t)nx * 4;
            float4 f0 = fp[0];
            float4 f1 = fp[1];
            float4 f2 = fp[2];
            float4 f3 = fp[3];
            unsigned nn = nxt[nx];
            s[0]  += f0.x; s[1]  += f0.y; s[2]  += f0.z; s[3]  += f0.w;
            s[4]  += f1.x; s[5]  += f1.y; s[6]  += f1.z; s[7]  += f1.w;
            s[8]  += f2.x; s[9]  += f2.y; s[10] += f2.z; s[11] += f2.w;
            s[12] += f3.x; s[13] += f3.y; s[14] += f3.z; s[15] += f3.w;
            cnt += 1.f;
            nx = nn;
        }

        if (cnt > 1.f) {                    // cnt==1: s/1 is exact, skip div
            float c = cnt;
#pragma unroll
            for (int q = 0; q < 16; ++q) s[q] /= c;
        }

        // Channel-major LDS write. addr = c*512 + idx: bank = idx%32 for all
        // c (512%32==0), lanes consecutive -> 2 lanes/bank (free on wave64).
        int idx = k * 256 + tid;
#pragma unroll
        for (int c = 0; c < 16; ++c) tile[c][idx] = s[c];
    }

    __syncthreads();

    // ---- Phase B: stream out. Wave w owns channels 4w..4w+3; per channel
    // writes VOX*4B = 2 KB contiguous (2 x float4 per lane).
    const int w = tid >> 6;
    const int l = tid & 63;
    float* obase = out + (size_t)b * C * V + v0;
#pragma unroll
    for (int cc = 0; cc < 4; ++cc) {
        int c = w * 4 + cc;
#pragma unroll
        for (int k = 0; k < VOX / 256; ++k) {   // 2 float4 instrs per channel
            int idx = k * 64 + l;               // float4 index within channel
            float4 val = *(const float4*)&tile[c][idx * 4];
            *(float4*)(obase + (size_t)c * V + idx * 4) = val;
        }
    }
}

// ---- Fallback (tiny-workspace safety net): direct strided atomics into out.
__global__ __launch_bounds__(256) void zero_f4(float4* __restrict__ p, int n4) {
    int i = blockIdx.x * blockDim.x + threadIdx.x;
    if (i < n4) p[i] = make_float4(0.f, 0.f, 0.f, 0.f);
}

__global__ __launch_bounds__(256) void count_only(
    const float* __restrict__ pts, float* __restrict__ counts) {
    int idx = blockIdx.x * blockDim.x + threadIdx.x;
    if (idx >= B * N) return;
    int b = idx >= N ? 1 : 0;
    const float* p = pts + (size_t)idx * 3;
    int v = voxel_of(p[0], p[1], p[2]);
    atomicAdd(counts + (size_t)b * V + v, 1.0f);
}

__global__ __launch_bounds__(256) void scatter_direct(
    const float* __restrict__ pts, const float* __restrict__ fts,
    const float* __restrict__ counts, float* __restrict__ out) {
    int idx = blockIdx.x * blockDim.x + threadIdx.x;
    if (idx >= B * N) return;
    int b = idx >= N ? 1 : 0;
    const float* p = pts + (size_t)idx * 3;
    int v = voxel_of(p[0], p[1], p[2]);
    float cnt = counts[(size_t)b * V + v];
    const float* f = fts + (size_t)idx * C;
    float* o = out + (size_t)b * C * V + v;
#pragma unroll
    for (int c = 0; c < 16; ++c) atomicAdd(o + (size_t)c * V, f[c] / cnt);
}

}  // namespace

extern "C" void kernel_launch(void* const* d_in, const int* in_sizes, int n_in,
                              void* d_out, int out_size, void* d_ws, size_t ws_size,
                              hipStream_t stream) {
    const float* pts = (const float*)d_in[0];   // [B, N, 3]
    const float* fts = (const float*)d_in[1];   // [B, N, C]
    float* out = (float*)d_out;                 // [B, C, D, H, W]

    const int n_pts = B * N;                    // 400,000
    const int pt_blocks = (n_pts + 255) / 256;

    const size_t head_bytes = (size_t)BV * sizeof(unsigned);      // 16.8 MB
    const size_t nxt_bytes = (size_t)n_pts * sizeof(unsigned);    // 1.6 MB

    if (ws_size >= head_bytes + nxt_bytes) {
        unsigned* head = (unsigned*)d_ws;
        unsigned* nxt = head + (size_t)BV;

        int head_n4 = BV / 4;  // 1,048,576
        init_head<<<(head_n4 + 255) / 256, 256, 0, stream>>>((uint4*)head, head_n4);
        build_list<<<pt_blocks, 256, 0, stream>>>(pts, head, nxt);

        int fin_blocks = BV / VOX;  // 8192
        finalize_tile<<<fin_blocks, 256, 0, stream>>>(
            head, nxt, (const float4*)fts, out);
    } else {
        // Safety net: direct atomic accumulation into out.
        float* counts = (float*)d_ws;
        int counts_f4 = BV / 4;
        zero_f4<<<(counts_f4 + 255) / 256, 256, 0, stream>>>((float4*)counts, counts_f4);
        int out_f4 = out_size / 4;
        zero_f4<<<(out_f4 + 255) / 256, 256, 0, stream>>>((float4*)out, out_f4);
        count_only<<<pt_blocks, 256, 0, stream>>>(pts, counts);
        scatter_direct<<<pt_blocks, 256, 0, stream>>>(pts, fts, counts, out);
    }
}